// Round 6
// baseline (978.791 us; speedup 1.0000x reference)
//
#include <hip/hip_runtime.h>
#include <math.h>

// ---------------------------------------------------------------------------
// Disentangler: 32 component-MLPs over sampled token rows + masked seg-pool.
// Round-6: 256^2-tile / 8-wave GEMMs (per-wave 128x64 -> 25% less LDS/FLOP),
// full-tile LDS double-buffer (128 KB), counted-vmcnt pipeline, operands
// pre-swizzled bf16 (Ab, Wt1, Wt2, h), pure global_load_lds staging, T1.
// ---------------------------------------------------------------------------

typedef __attribute__((ext_vector_type(8))) short bf16x8;
typedef __attribute__((ext_vector_type(4))) float f32x4;
typedef unsigned int u32;

constexpr int TT    = 16;
constexpr int TOKN  = 4096;
constexpr int DD    = 2048;
constexpr int HH    = 2048;
constexpr int CC    = 1024;
constexpr int LL    = 1000;
constexpr int NCOMP = 32;
constexpr int MP    = 1024;
constexpr int BK    = 64;
constexpr int MT256 = MP / 256;   // 4 m-tiles
constexpr int NT1X  = HH / 256;   // 8 n-tiles (gemm1)
constexpr int NT2X  = CC / 256;   // 4 n-tiles (gemm2)

__device__ __forceinline__ short f2bf(float f) {
  __bf16 h = (__bf16)f;
  return *reinterpret_cast<short*>(&h);
}
// Row swizzle (function of row mod 64): granule g of a 64-elem chunk lives at
// slot g ^ swz(row). Same layout in Ab, Wt1, Wt2, and h. 256-aligned tiles
// preserve it (offsets are 0 mod 64).
__device__ __forceinline__ int swz(int row) {
  return (row & 7) ^ ((row >> 3) & 7);
}
__device__ __forceinline__ int sw(int row, int gran) {   // short offset in LDS
  return (row << 6) + ((gran ^ swz(row)) << 3);
}
__device__ __forceinline__ void gl_lds16(const void* g, void* l) {
  __builtin_amdgcn_global_load_lds(
      (const __attribute__((address_space(1))) u32*)g,
      (__attribute__((address_space(3))) u32*)l, 16, 0, 0);
}

// --------------------------- dedup ----------------------------------------
__global__ void dedup_kernel(const int* __restrict__ ridx,
                             unsigned* __restrict__ bitmap,
                             float* __restrict__ keepf) {
  int comp = blockIdx.x;
  for (int l = threadIdx.x; l < MP; l += 256) {
    float kv = 0.0f;
    if (l < LL) {
      int r = ridx[comp * LL + l];
      unsigned bit = 1u << (r & 31);
      unsigned old = atomicOr(&bitmap[(comp << 10) + (r >> 5)], bit);
      kv = (old & bit) ? 0.0f : 1.0f;
    }
    keepf[(comp << 10) + l] = kv;
  }
}

// --------------------------- gather: x rows -> pre-swizzled bf16 -----------
__global__ __launch_bounds__(256) void gather_kernel(
    const float* __restrict__ x, const int* __restrict__ ridx,
    short* __restrict__ Ab) {
  int bid = blockIdx.x;
  int comp = bid >> 7, rgrp = bid & 127;
  int t = threadIdx.x;
  int tr = t >> 5, tn = t & 31;
  int m = rgrp * 8 + tr;
  int mi = m < LL ? m : LL - 1;
  int r = ridx[comp * LL + mi];
  int tokoff = comp >= 16 ? TOKN / 2 : 0;
  const float* src = x + ((size_t)(r >> 11) * TOKN + (r & 2047) + tokoff) * DD;
  short* drow = Ab + ((size_t)(comp * MP + m)) * DD;
  int s_m = swz(m);
#pragma unroll
  for (int i = 0; i < 8; ++i) {
    int gi = tn + 32 * i;
    float4 f0 = *reinterpret_cast<const float4*>(src + gi * 8);
    float4 f1 = *reinterpret_cast<const float4*>(src + gi * 8 + 4);
    bf16x8 pk;
    pk[0]=f2bf(f0.x); pk[1]=f2bf(f0.y); pk[2]=f2bf(f0.z); pk[3]=f2bf(f0.w);
    pk[4]=f2bf(f1.x); pk[5]=f2bf(f1.y); pk[6]=f2bf(f1.z); pk[7]=f2bf(f1.w);
    int c = gi >> 3, g = gi & 7;
    *reinterpret_cast<bf16x8*>(&drow[c * 64 + ((g ^ s_m) << 3)]) = pk;
  }
}

// --------------------------- transpose W -> pre-swizzled bf16 [n][k] -------
__global__ __launch_bounds__(256) void transW_kernel(
    const float* __restrict__ nsrc, const float* __restrict__ esrc,
    short* __restrict__ dst, int N, int NTt) {
  __shared__ float tile[64][65];
  int bid = blockIdx.x;
  int comp = bid / (32 * NTt);
  int rem = bid % (32 * NTt);
  int kt = rem / NTt, ntile = rem % NTt;
  int k0 = kt * 64, n0 = ntile * 64;
  const float* src = (comp < 16) ? nsrc + (size_t)comp * DD * N
                                 : esrc + (size_t)(comp - 16) * DD * N;
  int t = threadIdx.x;
  int kr = t >> 2, j0 = (t & 3) * 16;
  const float* sp = src + (size_t)(k0 + kr) * N + n0 + j0;
#pragma unroll
  for (int e = 0; e < 4; ++e) {
    float4 v = *reinterpret_cast<const float4*>(sp + 4 * e);
    tile[kr][j0 + 4*e]     = v.x;
    tile[kr][j0 + 4*e + 1] = v.y;
    tile[kr][j0 + 4*e + 2] = v.z;
    tile[kr][j0 + 4*e + 3] = v.w;
  }
  __syncthreads();
  int nr = t >> 2, i0 = (t & 3) * 16;
  int n = n0 + nr;
  int s_n = swz(n);
  short* drow = dst + ((size_t)comp * N + n) * DD;   // K == 2048 for W1 and W2
  int chunk = k0 >> 6;
#pragma unroll
  for (int h = 0; h < 2; ++h) {
    int g = ((i0 >> 3) + h) & 7;
    bf16x8 pk;
#pragma unroll
    for (int e = 0; e < 8; ++e) pk[e] = f2bf(tile[i0 + h * 8 + e][nr]);
    *reinterpret_cast<bf16x8*>(&drow[chunk * 64 + ((g ^ s_n) << 3)]) = pk;
  }
}

// --------------------------- GEMM1: h = gelu(x_sel @ W1 + b1) --------------
__global__ __launch_bounds__(512, 2) void gemm1_kernel(
    const float* __restrict__ nb1, const float* __restrict__ eb1,
    const short* __restrict__ Ab, const short* __restrict__ Wt1,
    short* __restrict__ hbuf) {
  __shared__ short smem[65536];   // 128 KB: A[2][16384] @0, B[2][16384] @32768

  constexpr int NWG = NCOMP * MT256 * NT1X;   // 1024
  constexpr int CPX = NWG / 8;
  int b0 = blockIdx.x;
  int lb = (b0 & 7) * CPX + (b0 >> 3);        // XCD-chunked (T1), bijective
  int comp = lb / (MT256 * NT1X);
  int rem  = lb % (MT256 * NT1X);
  int mt = rem / NT1X, nt = rem % NT1X;
  const float* b1 = (comp < 16) ? nb1 + (size_t)comp * HH
                                : eb1 + (size_t)(comp - 16) * HH;

  int tid = threadIdx.x, lane = tid & 63, wid = tid >> 6;
  int wr = wid >> 2, wc = wid & 3;            // 2M x 4N waves; wave tile 128x64
  int lr = lane & 15, lg = lane >> 4;

  const short* aSrc[4]; const short* bSrc[4]; int ldsOff[4];
#pragma unroll
  for (int q = 0; q < 4; ++q) {
    int f = q * 512 + tid, ar = f >> 3, sl = f & 7;
    aSrc[q] = Ab  + ((size_t)(comp * MP + mt * 256 + ar)) * DD + sl * 8;
    bSrc[q] = Wt1 + ((size_t)(comp * HH + nt * 256 + ar)) * DD + sl * 8;
    ldsOff[q] = f * 8;
  }

  f32x4 acc[8][4] = {};

  auto stage = [&](int t, int buf) {
    int nb = buf * 16384, off = t * 64;
#pragma unroll
    for (int q = 0; q < 4; ++q) gl_lds16(aSrc[q] + off, smem + nb + ldsOff[q]);
#pragma unroll
    for (int q = 0; q < 4; ++q) gl_lds16(bSrc[q] + off, smem + 32768 + nb + ldsOff[q]);
  };
  auto compute = [&](int buf) {
    const short* A = smem + buf * 16384;
    const short* B = smem + 32768 + buf * 16384;
#pragma unroll
    for (int kk = 0; kk < 2; ++kk) {
      bf16x8 af[8], bf_[4];
#pragma unroll
      for (int i = 0; i < 8; ++i)
        af[i] = *reinterpret_cast<const bf16x8*>(&A[sw(wr * 128 + i * 16 + lr, kk * 4 + lg)]);
#pragma unroll
      for (int j = 0; j < 4; ++j)
        bf_[j] = *reinterpret_cast<const bf16x8*>(&B[sw(wc * 64 + j * 16 + lr, kk * 4 + lg)]);
      __builtin_amdgcn_s_setprio(1);
#pragma unroll
      for (int i = 0; i < 8; ++i)
#pragma unroll
        for (int j = 0; j < 4; ++j)
          acc[i][j] = __builtin_amdgcn_mfma_f32_16x16x32_bf16(af[i], bf_[j], acc[i][j], 0, 0, 0);
      __builtin_amdgcn_s_setprio(0);
    }
  };

  constexpr int NTILE = DD / BK;   // 32
  stage(0, 0);
  stage(1, 1);
#pragma unroll 1
  for (int t = 0; t < NTILE - 1; ++t) {
    asm volatile("s_waitcnt vmcnt(8)" ::: "memory");   // tile t landed; t+1 in flight
    __builtin_amdgcn_sched_barrier(0);
    __builtin_amdgcn_s_barrier();
    compute(t & 1);
    __builtin_amdgcn_s_barrier();
    if (t + 2 < NTILE) stage(t + 2, t & 1);
  }
  asm volatile("s_waitcnt vmcnt(0)" ::: "memory");
  __builtin_amdgcn_sched_barrier(0);
  __builtin_amdgcn_s_barrier();
  compute((NTILE - 1) & 1);
  __builtin_amdgcn_s_barrier();

  // epilogue: +b1, exact gelu; two 128-row phases bounce through LDS, then
  // coalesced PRE-SWIZZLED bf16 h store (so gemm2 can global_load_lds it)
  short* Cs = smem;                            // stride 264 shorts
  const float* b1p = b1 + nt * 256;
#pragma unroll 1
  for (int p = 0; p < 2; ++p) {
    if (wr == p) {
#pragma unroll
      for (int i = 0; i < 8; ++i)
#pragma unroll
        for (int j = 0; j < 4; ++j) {
          int nl = wc * 64 + j * 16 + lr;
          float bias = b1p[nl];
#pragma unroll
          for (int rr = 0; rr < 4; ++rr) {
            int r = i * 16 + lg * 4 + rr;      // 0..127 within phase
            float v = acc[i][j][rr] + bias;
            float ge = 0.5f * v * (1.0f + erff(v * 0.70710678118654752f));
            Cs[r * 264 + nl] = f2bf(ge);
          }
        }
    }
    __syncthreads();
    short* hrow = hbuf + ((size_t)(comp * MP + mt * 256 + p * 128)) * HH;
#pragma unroll
    for (int q = 0; q < 8; ++q) {
      int f = q * 512 + tid;
      int r = f >> 5, g8 = f & 31;             // 32 8-short granules per row
      bf16x8 v = *reinterpret_cast<const bf16x8*>(&Cs[r * 264 + g8 * 8]);
      int dst = (nt * 4 + (g8 >> 3)) * 64 + (((g8 & 7) ^ swz(r)) << 3);
      *reinterpret_cast<bf16x8*>(&hrow[(size_t)r * HH + dst]) = v;
    }
    __syncthreads();
  }
}

// --------------------------- GEMM2: o = h @ W2 + b2, masked seg-reduce -----
__global__ __launch_bounds__(512, 2) void gemm2_kernel(
    const short* __restrict__ hbuf, const int* __restrict__ ridx,
    const float* __restrict__ nb2, const float* __restrict__ eb2,
    const short* __restrict__ Wt2,
    const float* __restrict__ keepf, float* __restrict__ partial) {
  __shared__ short smem[65536];

  constexpr int NWG = NCOMP * MT256 * NT2X;   // 512
  constexpr int CPX = NWG / 8;
  int b0 = blockIdx.x;
  int lb = (b0 & 7) * CPX + (b0 >> 3);
  int comp = lb / (MT256 * NT2X);
  int rem  = lb % (MT256 * NT2X);
  int mt = rem / NT2X, nt = rem % NT2X;
  const float* b2 = (comp < 16) ? nb2 + (size_t)comp * CC
                                : eb2 + (size_t)(comp - 16) * CC;

  int tid = threadIdx.x, lane = tid & 63, wid = tid >> 6;
  int wr = wid >> 2, wc = wid & 3;
  int lr = lane & 15, lg = lane >> 4;

  const short* aSrc[4]; const short* bSrc[4]; int ldsOff[4];
#pragma unroll
  for (int q = 0; q < 4; ++q) {
    int f = q * 512 + tid, ar = f >> 3, sl = f & 7;
    aSrc[q] = hbuf + ((size_t)(comp * MP + mt * 256 + ar)) * HH + sl * 8;
    bSrc[q] = Wt2  + ((size_t)(comp * CC + nt * 256 + ar)) * HH + sl * 8;
    ldsOff[q] = f * 8;
  }

  f32x4 acc[8][4] = {};

  auto stage = [&](int t, int buf) {
    int nb = buf * 16384, off = t * 64;
#pragma unroll
    for (int q = 0; q < 4; ++q) gl_lds16(aSrc[q] + off, smem + nb + ldsOff[q]);
#pragma unroll
    for (int q = 0; q < 4; ++q) gl_lds16(bSrc[q] + off, smem + 32768 + nb + ldsOff[q]);
  };
  auto compute = [&](int buf) {
    const short* A = smem + buf * 16384;
    const short* B = smem + 32768 + buf * 16384;
#pragma unroll
    for (int kk = 0; kk < 2; ++kk) {
      bf16x8 af[8], bf_[4];
#pragma unroll
      for (int i = 0; i < 8; ++i)
        af[i] = *reinterpret_cast<const bf16x8*>(&A[sw(wr * 128 + i * 16 + lr, kk * 4 + lg)]);
#pragma unroll
      for (int j = 0; j < 4; ++j)
        bf_[j] = *reinterpret_cast<const bf16x8*>(&B[sw(wc * 64 + j * 16 + lr, kk * 4 + lg)]);
      __builtin_amdgcn_s_setprio(1);
#pragma unroll
      for (int i = 0; i < 8; ++i)
#pragma unroll
        for (int j = 0; j < 4; ++j)
          acc[i][j] = __builtin_amdgcn_mfma_f32_16x16x32_bf16(af[i], bf_[j], acc[i][j], 0, 0, 0);
      __builtin_amdgcn_s_setprio(0);
    }
  };

  constexpr int NTILE = HH / BK;   // 32
  stage(0, 0);
  stage(1, 1);
#pragma unroll 1
  for (int t = 0; t < NTILE - 1; ++t) {
    asm volatile("s_waitcnt vmcnt(8)" ::: "memory");
    __builtin_amdgcn_sched_barrier(0);
    __builtin_amdgcn_s_barrier();
    compute(t & 1);
    __builtin_amdgcn_s_barrier();
    if (t + 2 < NTILE) stage(t + 2, t & 1);
  }
  asm volatile("s_waitcnt vmcnt(0)" ::: "memory");
  __builtin_amdgcn_sched_barrier(0);
  __builtin_amdgcn_s_barrier();
  compute((NTILE - 1) & 1);
  __builtin_amdgcn_s_barrier();

  // epilogue: (+b2) * keep, seg-reduce 256 rows by timestamp (LDS reused)
  float* part = (float*)smem;                  // 16*256 floats = 16 KB
  int*   tarr = (int*)((char*)smem + 16384);   // 256 ints
  float* karr = (float*)((char*)smem + 17408); // 256 floats
  if (tid < 256) {
    int mglob = mt * 256 + tid;
    int mi = mglob < LL ? mglob : LL - 1;
    int r2 = ridx[comp * LL + mi];
    tarr[tid] = r2 >> 11;
    karr[tid] = keepf[(comp << 10) + mglob];   // 0 for padded/duplicate rows
  }
  for (int e = tid; e < TT * 256; e += 512) part[e] = 0.0f;
  __syncthreads();
  const float* b2p = b2 + nt * 256;
#pragma unroll
  for (int i = 0; i < 8; ++i)
#pragma unroll
    for (int j = 0; j < 4; ++j) {
      int nl = wc * 64 + j * 16 + lr;
      float bias = b2p[nl];
#pragma unroll
      for (int rr = 0; rr < 4; ++rr) {
        int ml = wr * 128 + i * 16 + lg * 4 + rr;
        float v = (acc[i][j][rr] + bias) * karr[ml];
        atomicAdd(&part[tarr[ml] * 256 + nl], v);
      }
    }
  __syncthreads();
  float* pout = partial + ((size_t)(comp * MT256 + mt)) * TT * CC + nt * 256;
  for (int e = tid; e < TT * 256; e += 512) {
    int t2 = e >> 8, c = e & 255;
    pout[(size_t)t2 * CC + c] = part[e];
  }
}

// --------------------------- final reduce over m-tiles ---------------------
__global__ void reduce_kernel(const float* __restrict__ partial,
                              float* __restrict__ out) {
  int idx = blockIdx.x * 256 + threadIdx.x;     // = t*32768 + comp*1024 + c
  int c    = idx & (CC - 1);
  int comp = (idx >> 10) & (NCOMP - 1);
  int t    = idx >> 15;
  float s = 0.0f;
#pragma unroll
  for (int mt = 0; mt < MT256; ++mt)
    s += partial[(((size_t)(comp * MT256 + mt)) * TT + t) * CC + c];
  out[idx] = s * (1.0f / 4096.0f);
}

// ---------------------------------------------------------------------------
extern "C" void kernel_launch(void* const* d_in, const int* in_sizes, int n_in,
                              void* d_out, int out_size, void* d_ws, size_t ws_size,
                              hipStream_t stream) {
  const float* x    = (const float*)d_in[0];
  const int*   ridx = (const int*)d_in[3];
  const float* nW1  = (const float*)d_in[4];
  const float* nb1  = (const float*)d_in[5];
  const float* nW2  = (const float*)d_in[6];
  const float* nb2  = (const float*)d_in[7];
  const float* eW1  = (const float*)d_in[8];
  const float* eb1  = (const float*)d_in[9];
  const float* eW2  = (const float*)d_in[10];
  const float* eb2  = (const float*)d_in[11];
  float* out = (float*)d_out;

  // ws: [h 134MB][bitmap][keep][partial 8MB][Ab/Wt2 134MB][Wt1 268MB] ~546MB
  const size_t H_B   = (size_t)NCOMP * MP * HH * 2;
  const size_t BMP_B = (size_t)NCOMP * 1024 * 4;
  const size_t KP_B  = (size_t)NCOMP * 1024 * 4;
  const size_t PRT_B = (size_t)NCOMP * MT256 * TT * CC * 4;
  const size_t base  = H_B + BMP_B + KP_B + PRT_B;
  const size_t AB_B  = (size_t)NCOMP * MP * DD * 2;

  char* ws = (char*)d_ws;
  short* hbuf      = (short*)ws;
  unsigned* bitmap = (unsigned*)(ws + H_B);
  float* keepf     = (float*)(ws + H_B + BMP_B);
  float* partial   = (float*)(ws + H_B + BMP_B + KP_B);
  short* Ab        = (short*)(ws + base);            // reused as Wt2 later
  short* Wt1       = (short*)(ws + base + AB_B);

  hipMemsetAsync(bitmap, 0, BMP_B, stream);
  dedup_kernel<<<NCOMP, 256, 0, stream>>>(ridx, bitmap, keepf);
  gather_kernel<<<NCOMP * 128, 256, 0, stream>>>(x, ridx, Ab);
  transW_kernel<<<NCOMP * 32 * 32, 256, 0, stream>>>(nW1, eW1, Wt1, HH, 32);
  gemm1_kernel<<<NCOMP * MT256 * NT1X, 512, 0, stream>>>(nb1, eb1, Ab, Wt1, hbuf);
  transW_kernel<<<NCOMP * 32 * 16, 256, 0, stream>>>(nW2, eW2, Ab, CC, 16);
  gemm2_kernel<<<NCOMP * MT256 * NT2X, 512, 0, stream>>>(hbuf, ridx, nb2, eb2, Ab, keepf, partial);
  reduce_kernel<<<out_size / 256, 256, 0, stream>>>(partial, out);
}